// Round 12
// baseline (102.944 us; speedup 1.0000x reference)
//
#include <hip/hip_runtime.h>
#include <math.h>

#define KCOMP 8192
#define NSAMP 8192
#define BX 2048
#define DW 13

#define LOG2PI  1.8378770664093453f
#define LOGBETA 1.6094379124341003f   // ln(5)
#define LOGK    9.0109131020929380f   // ln(8192)
#define LOG2E   1.4426950408889634f
#define LN2     0.6931471805599453f
#define C2E     2.8853900817779268f   // 2*log2(e)

#define NBLK_KL   2048                // 128 rowtiles x 16 comp-chunks (512 comps each)
#define NBLK_DATA 1024                // 8 rows per block
#define NBLK_MONO (NBLK_KL + NBLK_DATA)

// knot table: yp(x) is a smooth 1-D function per row -> lerp from LDS.
#define NK     512
#define KSTR   520                    // table stride (words)
#define XLO    (-4.75f)
#define DXK    (9.5f / (float)NK)
#define USCALE ((float)NK / 9.5f)

typedef __attribute__((ext_vector_type(8))) short bf16x8_t;
typedef __attribute__((ext_vector_type(4))) float f32x4_t;

__device__ __forceinline__ float fast_log(float x) {
    return __builtin_amdgcn_logf(x) * LN2;
}
__device__ __forceinline__ float softplus_stable(float x) {
    return fmaxf(x, 0.0f) + log1pf(expf(-fabsf(x)));
}
__device__ __forceinline__ unsigned short to_bf16(float f) {
    unsigned int u = __builtin_bit_cast(unsigned int, f);
    u += 0x7FFFu + ((u >> 16) & 1u);
    return (unsigned short)(u >> 16);
}
__device__ __forceinline__ float from_bf16(unsigned short h) {
    unsigned int u = ((unsigned int)h) << 16;
    return __builtin_bit_cast(float, u);
}
// tanh pair from pre-scaled args a_i = 2*log2e*z_i, one shared rcp:
// 3 trans + 7 VALU per pair. Overflow d0*d1=inf -> t=1 (correct branch).
// Verified end-to-end R9-R11 (absmax 0.0).
__device__ __forceinline__ void tanh_pair(float a0, float a1, float& t0, float& t1) {
    float e0 = __builtin_amdgcn_exp2f(a0);
    float e1 = __builtin_amdgcn_exp2f(a1);
    float d0 = e0 + 1.0f, d1 = e1 + 1.0f;
    float inv = __builtin_amdgcn_rcpf(d0 * d1);
    t0 = fmaf(-2.0f, d1 * inv, 1.0f);
    t1 = fmaf(-2.0f, d0 * inv, 1.0f);
}

// ---- ws float offsets ----
#define OFF_PART  0        // float[1024]
#define OFF_RSUM  2048     // float[8192]  zeroed by prep
#define OFF_G2    10240    // float[8192]  f2*LOG2E
#define OFF_A2    18432    // float[8192]  f1*LOG2E
#define OFF_HQ    26624    // float[8192]  0.5||w||^2
#define OFF_PL    34816    // float[8192]  pivot*LOG2E
#define OFF_WF    43008    // float[8192*16]  f32 w, padded
#define OFF_WB    174080   // ushort[8192*32] hi/lo bf16 split of w
#define OFF_EMPB  305152   // ushort[8192*32] bf16(e) duplicated

// ================================================ prep: one job per thread, 16384 threads
__global__ __launch_bounds__(256) void prep_kernel(
        const float* __restrict__ emp, const float* __restrict__ rhos,
        const float* __restrict__ eps, const int* __restrict__ idxs,
        float* __restrict__ ws) {
    int g = blockIdx.x * 256 + threadIdx.x;     // 0..16383
    if (g < KCOMP) {
        int j = g;
        ws[OFF_RSUM + j] = 0.0f;
        unsigned short* empB = (unsigned short*)(ws + OFF_EMPB);
        float sp  = softplus_stable(rhos[j]);
        float var = sp * sp;
        float inv = 1.0f / var;
        float esq = 0.0f;
        #pragma unroll
        for (int c = 0; c < DW; ++c) {
            float e = emp[j * DW + c];
            esq = fmaf(e, e, esq);
            unsigned short eb = to_bf16(e);
            empB[j * 32 + c]      = eb;
            empB[j * 32 + 16 + c] = eb;
        }
        #pragma unroll
        for (int c = DW; c < 16; ++c) { empB[j*32+c] = 0; empB[j*32+16+c] = 0; }
        float f1v = -6.5f * (LOG2PI + logf(var)) - 0.5f * esq * inv;
        ws[OFF_G2 + j] = inv * LOG2E;
        ws[OFF_A2 + j] = f1v * LOG2E;
    } else {
        int b  = g - KCOMP;
        int i0 = idxs[b];
        unsigned short* wB = (unsigned short*)(ws + OFF_WB);
        float* wF = ws + OFF_WF;
        float sp  = softplus_stable(rhos[i0]);
        float var = sp * sp;
        float inv = 1.0f / var;
        float esq = 0.0f, wsq = 0.0f, dot = 0.0f;
        #pragma unroll
        for (int c = 0; c < DW; ++c) {
            float e  = emp[i0 * DW + c];
            float wc = fmaf(eps[b * DW + c], sp, e);
            esq = fmaf(e, e, esq);
            wsq = fmaf(wc, wc, wsq);
            dot = fmaf(wc, e, dot);
            wF[b * 16 + c] = wc;
            unsigned short hi = to_bf16(wc);
            wB[b * 32 + c]      = hi;
            wB[b * 32 + 16 + c] = to_bf16(wc - from_bf16(hi));
        }
        #pragma unroll
        for (int c = DW; c < 16; ++c) { wF[b*16+c] = 0.0f; wB[b*32+c] = 0; wB[b*32+16+c] = 0; }
        float f1v = -6.5f * (LOG2PI + logf(var)) - 0.5f * esq * inv;
        float h   = 0.5f * wsq;
        ws[OFF_HQ + b] = h;
        ws[OFF_PL + b] = fmaf(inv, dot - h, f1v) * LOG2E;
    }
}

// ================================================ main: kl (blocks 0..2047) + data (2048..3071)
__global__ __launch_bounds__(256) void main_kernel(
        float* __restrict__ ws, const float* __restrict__ x,
        const float* __restrict__ y) {
    __shared__ float kn[8 * KSTR];    // 8 knot tables, 16.6 KB
    __shared__ float red[4];
    int tid = threadIdx.x, wave = tid >> 6, lane = tid & 63;

    float* part = ws + OFF_PART;
    float* rsum = ws + OFF_RSUM;
    const float* G2  = ws + OFF_G2;
    const float* A2  = ws + OFF_A2;
    const float* hqA = ws + OFF_HQ;
    const float* plA = ws + OFF_PL;
    const float* wF  = ws + OFF_WF;
    const unsigned short* wB   = (const unsigned short*)(ws + OFF_WB);
    const unsigned short* empB = (const unsigned short*)(ws + OFF_EMPB);

    if (blockIdx.x >= NBLK_KL) {
        // ---------------- data role: 8 rows/block ----------------
        int d = blockIdx.x - NBLK_KL;

        // phase 1: 32 threads per table; thread loads its row's weights once,
        // evaluates 16 knots (even packing, no straggler iteration).
        {
            int t   = tid >> 5;            // table / local row 0..7
            int sub = tid & 31;
            int row = d * 8 + t;
            float wv[DW];
            #pragma unroll
            for (int c = 0; c < DW; ++c) wv[c] = wF[row * 16 + c];
            float s0 = wv[0]*C2E, s1 = wv[1]*C2E, s2 = wv[2]*C2E, s3 = wv[3]*C2E;
            float s4 = wv[4]*C2E, s5 = wv[5]*C2E, s6 = wv[6]*C2E, s7 = wv[7]*C2E;
            float s8 = wv[8]*C2E, s9 = wv[9]*C2E;
            float* knw = kn + t * KSTR;
            for (int idx = sub; idx <= NK; idx += 32) {
                float xk = fmaf((float)idx, DXK, XLO);
                float h10, h11, h20, h21;
                tanh_pair(fmaf(s0, xk, s2), fmaf(s1, xk, s3), h10, h11);
                tanh_pair(fmaf(s4, h10, fmaf(s5, h11, s8)),
                          fmaf(s6, h10, fmaf(s7, h11, s9)), h20, h21);
                knw[idx] = fmaf(wv[10], h20, fmaf(wv[11], h21, wv[12]));
            }
        }
        __syncthreads();

        // phase 2: wave w takes x-chunk w (512 pts), lerps ALL 8 tables;
        // u/i/f computed once per point (8x index-math amortization).
        float acc = 0.0f;
        #pragma unroll 2
        for (int it = 0; it < 8; ++it) {
            int k = wave * 512 + it * 64 + lane;
            float tt = x[k];
            float yv = y[k];
            float u = fmaf(tt, USCALE, (float)(NK / 2));
            u = fminf(fmaxf(u, 0.0f), (float)NK - 0.001f);
            int   i = (int)u;
            float f = u - (float)i;
            #pragma unroll
            for (int t = 0; t < 8; ++t) {
                float a = kn[t * KSTR + i];
                float b = kn[t * KSTR + i + 1];
                float dd = fmaf(f, b - a, a) - yv;
                acc = fmaf(dd, dd, acc);
            }
        }
        #pragma unroll
        for (int o = 32; o; o >>= 1) acc += __shfl_down(acc, o);
        if (lane == 0) red[wave] = acc;
        __syncthreads();
        if (tid == 0) part[d] = red[0] + red[1] + red[2] + red[3];
    } else {
        // ---------------- kl role: MFMA GEMM + fused exp epilogue ----------------
        int bid     = blockIdx.x;              // 0..2047
        int rowtile = bid & 127;
        int chunk   = bid >> 7;                // 0..15 (512 comps each: short blocks, tail-packing)
        int rowbase = rowtile * 64 + wave * 16;
        int half = lane >> 4;
        int m16  = lane & 15;

        const bf16x8_t afrag = *(const bf16x8_t*)(wB + (rowbase + m16) * 32 + half * 8);
        float h[4], p[4];
        #pragma unroll
        for (int r = 0; r < 4; ++r) {
            h[r] = hqA[rowbase + half * 4 + r];
            p[r] = plA[rowbase + half * 4 + r];
        }
        float s[4] = {0.f, 0.f, 0.f, 0.f};

        int j0 = chunk * (KCOMP / 16);
        #pragma unroll 2
        for (int jt = 0; jt < (KCOMP / 16) / 16; ++jt) {
            int j = j0 + jt * 16 + m16;
            bf16x8_t bfrag = *(const bf16x8_t*)(empB + j * 32 + half * 8);
            f32x4_t c = {0.f, 0.f, 0.f, 0.f};
            c = __builtin_amdgcn_mfma_f32_16x16x32_bf16(afrag, bfrag, c, 0, 0, 0);
            float g2 = G2[j], a2 = A2[j];
            #pragma unroll
            for (int r = 0; r < 4; ++r) {
                float t = fmaf(-g2, h[r], a2 - p[r]);
                s[r] += __builtin_amdgcn_exp2f(fmaf(g2, c[r], t));
            }
        }
        #pragma unroll
        for (int r = 0; r < 4; ++r) {
            float S = s[r];
            S += __shfl_xor(S, 1); S += __shfl_xor(S, 2);
            S += __shfl_xor(S, 4); S += __shfl_xor(S, 8);
            if (m16 == 0) atomicAdd(&rsum[rowbase + half * 4 + r], S);
        }
    }
}

// ================================================ finalize (1024 threads)
__global__ __launch_bounds__(1024) void fin_kernel(
        const float* __restrict__ ws, float* __restrict__ out) {
    __shared__ float red1[16], red2[16];
    int tid = threadIdx.x, wave = tid >> 6, lane = tid & 63;

    const float* part = ws + OFF_PART;
    const float* rsum = ws + OFF_RSUM;
    const float* hqA  = ws + OFF_HQ;
    const float* plA  = ws + OFF_PL;

    float s1 = 0.0f;
    for (int i = tid; i < NBLK_DATA; i += 1024) s1 += part[i];
    float s2 = 0.0f;
    for (int b = tid; b < NSAMP; b += 1024) {
        float q     = plA[b] * LN2 + fast_log(rsum[b]) - LOGK;
        float prior = -hqA[b] - 6.5f * LOG2PI;
        s2 += q - prior;
    }
    #pragma unroll
    for (int o = 32; o; o >>= 1) { s1 += __shfl_down(s1, o); s2 += __shfl_down(s2, o); }
    if (lane == 0) { red1[wave] = s1; red2[wave] = s2; }
    __syncthreads();
    if (tid < 16) {
        s1 = red1[tid]; s2 = red2[tid];
        #pragma unroll
        for (int o = 8; o; o >>= 1) { s1 += __shfl_down(s1, o); s2 += __shfl_down(s2, o); }
        if (tid == 0) {
            float data_lp = -2.5f * s1 / (float)NSAMP
                            + (float)BX * 0.5f * (LOGBETA - LOG2PI);
            out[0] = data_lp - s2 / (float)NSAMP;
        }
    }
}

extern "C" void kernel_launch(void* const* d_in, const int* in_sizes, int n_in,
                              void* d_out, int out_size, void* d_ws, size_t ws_size,
                              hipStream_t stream) {
    const float* emp  = (const float*)d_in[0];
    const float* rhos = (const float*)d_in[1];
    const float* x    = (const float*)d_in[2];
    const float* y    = (const float*)d_in[3];
    const float* eps  = (const float*)d_in[4];
    const int*   idxs = (const int*)d_in[5];
    float* out = (float*)d_out;
    float* ws  = (float*)d_ws;

    prep_kernel<<<64, 256, 0, stream>>>(emp, rhos, eps, idxs, ws);
    main_kernel<<<NBLK_MONO, 256, 0, stream>>>(ws, x, y);
    fin_kernel<<<1, 1024, 0, stream>>>(ws, out);
}

// Round 13
// 96.173 us; speedup vs baseline: 1.0704x; 1.0704x over previous
//
#include <hip/hip_runtime.h>
#include <math.h>

#define KCOMP 8192
#define NSAMP 8192
#define BX 2048
#define DW 13

#define LOG2PI  1.8378770664093453f
#define LOGBETA 1.6094379124341003f   // ln(5)
#define LOGK    9.0109131020929380f   // ln(8192)
#define LOG2E   1.4426950408889634f
#define LN2     0.6931471805599453f
#define C2E     2.8853900817779268f   // 2*log2(e)

#define NBLK_KL   1024                // 128 rowtiles x 8 comp-chunks (R11-proven)
#define NBLK_DATA 2048                // 4 rows per block, 8.3 KB LDS (R11-proven)
#define NBLK_MONO (NBLK_KL + NBLK_DATA)

// knot table: yp(x) is a smooth 1-D function per row -> lerp from LDS.
#define NK     512
#define KSTR   520                    // table stride (words)
#define XLO    (-4.75f)
#define DXK    (9.5f / (float)NK)
#define USCALE ((float)NK / 9.5f)

typedef __attribute__((ext_vector_type(8))) short bf16x8_t;
typedef __attribute__((ext_vector_type(4))) float f32x4_t;

__device__ __forceinline__ float fast_log(float x) {
    return __builtin_amdgcn_logf(x) * LN2;
}
__device__ __forceinline__ float softplus_stable(float x) {
    return fmaxf(x, 0.0f) + log1pf(expf(-fabsf(x)));
}
__device__ __forceinline__ unsigned short to_bf16(float f) {
    unsigned int u = __builtin_bit_cast(unsigned int, f);
    u += 0x7FFFu + ((u >> 16) & 1u);
    return (unsigned short)(u >> 16);
}
__device__ __forceinline__ float from_bf16(unsigned short h) {
    unsigned int u = ((unsigned int)h) << 16;
    return __builtin_bit_cast(float, u);
}
// tanh pair from pre-scaled args a_i = 2*log2e*z_i, one shared rcp:
// 3 trans + 7 VALU per pair. Overflow d0*d1=inf -> t=1 (correct branch).
// Verified end-to-end R9-R12 (absmax 0.0).
__device__ __forceinline__ void tanh_pair(float a0, float a1, float& t0, float& t1) {
    float e0 = __builtin_amdgcn_exp2f(a0);
    float e1 = __builtin_amdgcn_exp2f(a1);
    float d0 = e0 + 1.0f, d1 = e1 + 1.0f;
    float inv = __builtin_amdgcn_rcpf(d0 * d1);
    t0 = fmaf(-2.0f, d1 * inv, 1.0f);
    t1 = fmaf(-2.0f, d0 * inv, 1.0f);
}

// ---- ws float offsets ----
#define OFF_PART  0        // float[2048]
#define OFF_RSUM  2048     // float[8192]  zeroed by prep
#define OFF_G2    10240    // float[8192]  f2*LOG2E
#define OFF_A2    18432    // float[8192]  f1*LOG2E
#define OFF_HQ    26624    // float[8192]  0.5||w||^2
#define OFF_PL    34816    // float[8192]  pivot*LOG2E
#define OFF_WF    43008    // float[8192*16]  f32 w, padded
#define OFF_WB    174080   // ushort[8192*32] hi/lo bf16 split of w
#define OFF_EMPB  305152   // ushort[8192*32] bf16(e) duplicated

// ================================================ prep: 256 blocks x 64 (full CU coverage)
__global__ __launch_bounds__(64) void prep_kernel(
        const float* __restrict__ emp, const float* __restrict__ rhos,
        const float* __restrict__ eps, const int* __restrict__ idxs,
        float* __restrict__ ws) {
    int g = blockIdx.x * 64 + threadIdx.x;      // 0..16383
    if (g < KCOMP) {
        int j = g;
        ws[OFF_RSUM + j] = 0.0f;
        unsigned short* empB = (unsigned short*)(ws + OFF_EMPB);
        float sp  = softplus_stable(rhos[j]);
        float var = sp * sp;
        float inv = 1.0f / var;
        float esq = 0.0f;
        #pragma unroll
        for (int c = 0; c < DW; ++c) {
            float e = emp[j * DW + c];
            esq = fmaf(e, e, esq);
            unsigned short eb = to_bf16(e);
            empB[j * 32 + c]      = eb;
            empB[j * 32 + 16 + c] = eb;
        }
        #pragma unroll
        for (int c = DW; c < 16; ++c) { empB[j*32+c] = 0; empB[j*32+16+c] = 0; }
        float f1v = -6.5f * (LOG2PI + logf(var)) - 0.5f * esq * inv;
        ws[OFF_G2 + j] = inv * LOG2E;
        ws[OFF_A2 + j] = f1v * LOG2E;
    } else {
        int b  = g - KCOMP;
        int i0 = idxs[b];
        unsigned short* wB = (unsigned short*)(ws + OFF_WB);
        float* wF = ws + OFF_WF;
        float sp  = softplus_stable(rhos[i0]);
        float var = sp * sp;
        float inv = 1.0f / var;
        float esq = 0.0f, wsq = 0.0f, dot = 0.0f;
        #pragma unroll
        for (int c = 0; c < DW; ++c) {
            float e  = emp[i0 * DW + c];
            float wc = fmaf(eps[b * DW + c], sp, e);
            esq = fmaf(e, e, esq);
            wsq = fmaf(wc, wc, wsq);
            dot = fmaf(wc, e, dot);
            wF[b * 16 + c] = wc;
            unsigned short hi = to_bf16(wc);
            wB[b * 32 + c]      = hi;
            wB[b * 32 + 16 + c] = to_bf16(wc - from_bf16(hi));
        }
        #pragma unroll
        for (int c = DW; c < 16; ++c) { wF[b*16+c] = 0.0f; wB[b*32+c] = 0; wB[b*32+16+c] = 0; }
        float f1v = -6.5f * (LOG2PI + logf(var)) - 0.5f * esq * inv;
        float h   = 0.5f * wsq;
        ws[OFF_HQ + b] = h;
        ws[OFF_PL + b] = fmaf(inv, dot - h, f1v) * LOG2E;
    }
}

// ================================================ main: kl (blocks 0..1023) + data (1024..3071)
__global__ __launch_bounds__(256) void main_kernel(
        float* __restrict__ ws, const float* __restrict__ x,
        const float* __restrict__ y) {
    __shared__ float kn[4 * KSTR];    // 4 knot tables, 8.3 KB (kl occupancy intact)
    __shared__ float red[4];
    int tid = threadIdx.x, wave = tid >> 6, lane = tid & 63;

    float* part = ws + OFF_PART;
    float* rsum = ws + OFF_RSUM;
    const float* G2  = ws + OFF_G2;
    const float* A2  = ws + OFF_A2;
    const float* hqA = ws + OFF_HQ;
    const float* plA = ws + OFF_PL;
    const float* wF  = ws + OFF_WF;
    const unsigned short* wB   = (const unsigned short*)(ws + OFF_WB);
    const unsigned short* empB = (const unsigned short*)(ws + OFF_EMPB);

    if (blockIdx.x >= NBLK_KL) {
        // ---------------- data role: 4 rows/block ----------------
        int d = blockIdx.x - NBLK_KL;

        // phase 1: wave w fills table w for row d*4+w
        {
            int row = d * 4 + wave;
            float wv[DW];
            #pragma unroll
            for (int c = 0; c < DW; ++c) wv[c] = wF[row * 16 + c];
            float s0 = wv[0]*C2E, s1 = wv[1]*C2E, s2 = wv[2]*C2E, s3 = wv[3]*C2E;
            float s4 = wv[4]*C2E, s5 = wv[5]*C2E, s6 = wv[6]*C2E, s7 = wv[7]*C2E;
            float s8 = wv[8]*C2E, s9 = wv[9]*C2E;
            float* knw = kn + wave * KSTR;
            #pragma unroll
            for (int kk = 0; kk < NK / 64 + 1; ++kk) {
                int idx = kk * 64 + lane;
                if (idx <= NK) {
                    float xk = fmaf((float)idx, DXK, XLO);
                    float h10, h11, h20, h21;
                    tanh_pair(fmaf(s0, xk, s2), fmaf(s1, xk, s3), h10, h11);
                    tanh_pair(fmaf(s4, h10, fmaf(s5, h11, s8)),
                              fmaf(s6, h10, fmaf(s7, h11, s9)), h20, h21);
                    knw[idx] = fmaf(wv[10], h20, fmaf(wv[11], h21, wv[12]));
                }
            }
        }
        __syncthreads();

        // phase 2: wave w takes x-chunk w (512 pts, float4), lerps ALL 4 tables;
        // u/i/f computed once per point (4x index-math amortization).
        const float* tb0 = kn;
        const float* tb1 = kn + KSTR;
        const float* tb2 = kn + 2 * KSTR;
        const float* tb3 = kn + 3 * KSTR;
        const float4* x4 = (const float4*)x;
        const float4* y4 = (const float4*)y;
        float acc = 0.0f;
        #pragma unroll
        for (int it = 0; it < 2; ++it) {
            int k0 = wave * 128 + it * 64 + lane;
            float4 tv = x4[k0];
            float4 yv = y4[k0];
            float tt[4] = {tv.x, tv.y, tv.z, tv.w};
            float yy[4] = {yv.x, yv.y, yv.z, yv.w};
            #pragma unroll
            for (int p = 0; p < 4; ++p) {
                float u = fmaf(tt[p], USCALE, (float)(NK / 2));
                u = fminf(fmaxf(u, 0.0f), (float)NK - 0.001f);
                int   i = (int)u;
                float f = u - (float)i;
                float a0 = tb0[i], b0 = tb0[i + 1];
                float a1 = tb1[i], b1 = tb1[i + 1];
                float a2 = tb2[i], b2 = tb2[i + 1];
                float a3 = tb3[i], b3 = tb3[i + 1];
                float d0 = fmaf(f, b0 - a0, a0) - yy[p];
                float d1 = fmaf(f, b1 - a1, a1) - yy[p];
                float d2 = fmaf(f, b2 - a2, a2) - yy[p];
                float d3 = fmaf(f, b3 - a3, a3) - yy[p];
                acc = fmaf(d0, d0, acc);
                acc = fmaf(d1, d1, acc);
                acc = fmaf(d2, d2, acc);
                acc = fmaf(d3, d3, acc);
            }
        }
        #pragma unroll
        for (int o = 32; o; o >>= 1) acc += __shfl_down(acc, o);
        if (lane == 0) red[wave] = acc;
        __syncthreads();
        if (tid == 0) part[d] = red[0] + red[1] + red[2] + red[3];
    } else {
        // ---------------- kl role: MFMA GEMM + fused exp epilogue ----------------
        int bid     = blockIdx.x;              // 0..1023
        int rowtile = bid & 127;
        int chunk   = bid >> 7;                // 0..7
        int rowbase = rowtile * 64 + wave * 16;
        int half = lane >> 4;
        int m16  = lane & 15;

        const bf16x8_t afrag = *(const bf16x8_t*)(wB + (rowbase + m16) * 32 + half * 8);
        float h[4], p[4];
        #pragma unroll
        for (int r = 0; r < 4; ++r) {
            h[r] = hqA[rowbase + half * 4 + r];
            p[r] = plA[rowbase + half * 4 + r];
        }
        float s[4] = {0.f, 0.f, 0.f, 0.f};

        int j0 = chunk * (KCOMP / 8);
        #pragma unroll 2
        for (int jt = 0; jt < (KCOMP / 8) / 16; ++jt) {
            int j = j0 + jt * 16 + m16;
            bf16x8_t bfrag = *(const bf16x8_t*)(empB + j * 32 + half * 8);
            f32x4_t c = {0.f, 0.f, 0.f, 0.f};
            c = __builtin_amdgcn_mfma_f32_16x16x32_bf16(afrag, bfrag, c, 0, 0, 0);
            float g2 = G2[j], a2 = A2[j];
            #pragma unroll
            for (int r = 0; r < 4; ++r) {
                float t = fmaf(-g2, h[r], a2 - p[r]);
                s[r] += __builtin_amdgcn_exp2f(fmaf(g2, c[r], t));
            }
        }
        #pragma unroll
        for (int r = 0; r < 4; ++r) {
            float S = s[r];
            S += __shfl_xor(S, 1); S += __shfl_xor(S, 2);
            S += __shfl_xor(S, 4); S += __shfl_xor(S, 8);
            if (m16 == 0) atomicAdd(&rsum[rowbase + half * 4 + r], S);
        }
    }
}

// ================================================ finalize (1024 threads)
__global__ __launch_bounds__(1024) void fin_kernel(
        const float* __restrict__ ws, float* __restrict__ out) {
    __shared__ float red1[16], red2[16];
    int tid = threadIdx.x, wave = tid >> 6, lane = tid & 63;

    const float* part = ws + OFF_PART;
    const float* rsum = ws + OFF_RSUM;
    const float* hqA  = ws + OFF_HQ;
    const float* plA  = ws + OFF_PL;

    float s1 = 0.0f;
    for (int i = tid; i < NBLK_DATA; i += 1024) s1 += part[i];
    float s2 = 0.0f;
    for (int b = tid; b < NSAMP; b += 1024) {
        float q     = plA[b] * LN2 + fast_log(rsum[b]) - LOGK;
        float prior = -hqA[b] - 6.5f * LOG2PI;
        s2 += q - prior;
    }
    #pragma unroll
    for (int o = 32; o; o >>= 1) { s1 += __shfl_down(s1, o); s2 += __shfl_down(s2, o); }
    if (lane == 0) { red1[wave] = s1; red2[wave] = s2; }
    __syncthreads();
    if (tid < 16) {
        s1 = red1[tid]; s2 = red2[tid];
        #pragma unroll
        for (int o = 8; o; o >>= 1) { s1 += __shfl_down(s1, o); s2 += __shfl_down(s2, o); }
        if (tid == 0) {
            float data_lp = -2.5f * s1 / (float)NSAMP
                            + (float)BX * 0.5f * (LOGBETA - LOG2PI);
            out[0] = data_lp - s2 / (float)NSAMP;
        }
    }
}

extern "C" void kernel_launch(void* const* d_in, const int* in_sizes, int n_in,
                              void* d_out, int out_size, void* d_ws, size_t ws_size,
                              hipStream_t stream) {
    const float* emp  = (const float*)d_in[0];
    const float* rhos = (const float*)d_in[1];
    const float* x    = (const float*)d_in[2];
    const float* y    = (const float*)d_in[3];
    const float* eps  = (const float*)d_in[4];
    const int*   idxs = (const int*)d_in[5];
    float* out = (float*)d_out;
    float* ws  = (float*)d_ws;

    prep_kernel<<<256, 64, 0, stream>>>(emp, rhos, eps, idxs, ws);
    main_kernel<<<NBLK_MONO, 256, 0, stream>>>(ws, x, y);
    fin_kernel<<<1, 1024, 0, stream>>>(ws, out);
}